// Round 18
// baseline (192.847 us; speedup 1.0000x reference)
//
#include <hip/hip_runtime.h>

// Problem constants
#define SEQ 2048
#define HID 2048
#define NH 16
#define NKVH 4
#define HDIM 128
#define NB 2
#define MTOT (NB * SEQ)          // 4096 rows
#define QKV_N (NH * HDIM + 2 * NKVH * HDIM)  // 3072
#define OUT0_ELEMS (NB * SEQ * HID)          // 8,388,608
#define ATTN_ELEMS ((size_t)NB * NH * SEQ * SEQ) // 134,217,728
// zero-fill partition (R16 rebalance: G2 was write-bound, G1 compute-bound):
// attn 4096 x 768 + GEMM1 768 x 27162 + GEMM2 512 x 18649
#define ZA_CHUNK 768
#define ZA_TOTAL ((long)4096 * ZA_CHUNK)     // 3,145,728
#define Z1_CHUNK 27162
#define Z1_TOTAL ((long)768 * Z1_CHUNK)      // 20,860,416
#define Z2_CHUNK 18649                       // 512*18649 = 9,548,288; sum = 33,554,432

typedef __bf16 bf16x8 __attribute__((ext_vector_type(8)));
typedef float f32x4 __attribute__((ext_vector_type(4)));

__device__ __forceinline__ unsigned short f2bf(float f) {
  unsigned int u = __float_as_uint(f);
  u += 0x7FFFu + ((u >> 16) & 1u);   // round-to-nearest-even
  return (unsigned short)(u >> 16);
}
__device__ __forceinline__ float bf2f(unsigned short u) {
  return __uint_as_float(((unsigned int)u) << 16);
}

// ---------------- fused prep: x->bf16 cvt + wq/wk/wv transpose+cvt ------------
// (Wot transpose lives in attn_k's grid — only GEMM2 needs it.)
__global__ __launch_bounds__(256) void prep_k(
    const float* __restrict__ x, const float* __restrict__ wq,
    const float* __restrict__ wk, const float* __restrict__ wv,
    unsigned short* __restrict__ Xbf, unsigned short* __restrict__ Wqkvt) {
  __shared__ float tile[32][33];
  const int bid = blockIdx.x, t = threadIdx.x;
  if (bid < 8192) {
    int i = bid * 256 + t;
    float4 v = ((const float4*)x)[i];
    ushort4 o;
    o.x = f2bf(v.x); o.y = f2bf(v.y); o.z = f2bf(v.z); o.w = f2bf(v.w);
    ((ushort4*)Xbf)[i] = o;
    return;
  }
  int lb = bid - 8192;
  const float* W; unsigned short* Wt; int gx, N;
  if (lb < 4096)      { W = wq; Wt = Wqkvt;                       gx = 64; N = 2048; }
  else if (lb < 5120) { W = wk; Wt = Wqkvt + (size_t)2048 * HID;  gx = 16; N = 512;  lb -= 4096; }
  else                { W = wv; Wt = Wqkvt + (size_t)2560 * HID;  gx = 16; N = 512;  lb -= 5120; }
  const int n0 = (lb % gx) * 32, k0 = (lb / gx) * 32;
  const int tx = t & 31, ty = t >> 5;
  #pragma unroll
  for (int r = 0; r < 32; r += 8)
    tile[ty + r][tx] = W[(size_t)(k0 + ty + r) * N + n0 + tx];
  __syncthreads();
  #pragma unroll
  for (int r = 0; r < 32; r += 8)
    Wt[(size_t)(n0 + ty + r) * HID + k0 + tx] = f2bf(tile[tx][ty + r]);
}

// ---------------- bf16 MFMA GEMM (m97 structure, BK=64) + fused attn-zero job -
// 128x128 tile, 4 waves x 4x4 frags of 16x16x32, BK=64, global_load_lds w=16,
// XCD-aware swizzle, zero-stores in compute phase (free under MFMA in G1).
template <bool OUT_BF16>
__global__ __launch_bounds__(256, 4) void gemm_bt_k(
    const unsigned short* __restrict__ A, const unsigned short* __restrict__ Bt,
    void* __restrict__ Cv, int M, int N, int K,
    f32x4* __restrict__ attn4, long zoff, int zchunk) {
  __shared__ unsigned short As[128 * 64];   // 16 KB
  __shared__ unsigned short Bs[128 * 64];   // 16 KB
  const int t = threadIdx.x;
  // XCD swizzle (nwg % 8 == 0 for both GEMMs)
  const int nbx = gridDim.x;
  const int rawbid = blockIdx.y * nbx + blockIdx.x;
  const int nwg = nbx * gridDim.y;
  const int sw = (rawbid & 7) * (nwg >> 3) + (rawbid >> 3);
  const int row0 = (sw / nbx) << 7;
  const int col0 = (sw % nbx) << 7;
  const int lane = t & 63;
  const int wave = t >> 6;
  const int wr = (wave >> 1) << 6;
  const int wc = (wave & 1) << 6;
  const int lrow = lane & 15;
  const int kofs = (lane >> 4) << 3;

  const long zbase = zoff + (long)rawbid * zchunk;

  f32x4 acc[4][4];
  #pragma unroll
  for (int a = 0; a < 4; ++a)
    #pragma unroll
    for (int b = 0; b < 4; ++b)
      #pragma unroll
      for (int r = 0; r < 4; ++r) acc[a][b][r] = 0.f;

  // staging: tile = 128 rows x 64 cols bf16 = 1024 x 16B chunks; 256 thr x 4.
  const unsigned short* Ab = A + (size_t)row0 * K;
  const unsigned short* Bb = Bt + (size_t)col0 * K;

  const int nk = K >> 6;
  for (int kt = 0; kt < nk; ++kt) {
    const int k0 = kt << 6;
    if (kt) __syncthreads();
    #pragma unroll
    for (int i = 0; i < 4; ++i) {
      const int c = i * 256 + t;          // all 1024 chunks covered
      const int row = c >> 3, c8 = (c & 7) << 3;
      __builtin_amdgcn_global_load_lds(
          (const __attribute__((address_space(1))) void*)(Ab + (size_t)row * K + k0 + c8),
          (__attribute__((address_space(3))) void*)(As + c * 8), 16, 0, 0);
      __builtin_amdgcn_global_load_lds(
          (const __attribute__((address_space(1))) void*)(Bb + (size_t)row * K + k0 + c8),
          (__attribute__((address_space(3))) void*)(Bs + c * 8), 16, 0, 0);
    }
    __syncthreads();   // compiler drains vmcnt(0)

    // fused attn-zero side job: 4 chunks per K-step (retire during MFMA phase)
    #pragma unroll
    for (int s = 0; s < 4; ++s) {
      int il = (kt * 4 + s) * 256 + t;
      if (il < zchunk) {
        long g = zbase + il;
        int c = (int)(g & 511);               // f32x4 chunk within attn row
        int i = (int)((g >> 9) & (SEQ - 1));  // query index of this row
        int hi = i >> 2;
        int lo = (i >= 2 ? i - 2 : 0) >> 2;
        if (c != hi && c != lo) {
          f32x4 z = {0.f, 0.f, 0.f, 0.f};
          __builtin_nontemporal_store(z, attn4 + g);
        }
      }
    }

    #pragma unroll
    for (int ks = 0; ks < 2; ++ks) {
      bf16x8 af[4], bfr[4];
      #pragma unroll
      for (int mf = 0; mf < 4; ++mf)
        af[mf] = *(const bf16x8*)(As + ((wr + mf * 16 + lrow) << 6) + (ks << 5) + kofs);
      #pragma unroll
      for (int nf = 0; nf < 4; ++nf)
        bfr[nf] = *(const bf16x8*)(Bs + ((wc + nf * 16 + lrow) << 6) + (ks << 5) + kofs);
      #pragma unroll
      for (int mf = 0; mf < 4; ++mf)
        #pragma unroll
        for (int nf = 0; nf < 4; ++nf)
          acc[mf][nf] = __builtin_amdgcn_mfma_f32_16x16x32_bf16(af[mf], bfr[nf],
                                                                acc[mf][nf], 0, 0, 0);
    }
  }

  // epilogue: D mapping col=lane&15, row=(lane>>4)*4+reg  [measured m89/m91]
  const int cr = row0 + wr + ((lane >> 4) << 2);
  const int cc = col0 + wc + (lane & 15);
  #pragma unroll
  for (int mf = 0; mf < 4; ++mf)
    #pragma unroll
    for (int nf = 0; nf < 4; ++nf)
      #pragma unroll
      for (int r = 0; r < 4; ++r) {
        size_t idx = (size_t)(cr + mf * 16 + r) * N + cc + nf * 16;
        if constexpr (OUT_BF16)
          ((unsigned short*)Cv)[idx] = f2bf(acc[mf][nf][r]);
        else
          ((float*)Cv)[idx] = acc[mf][nf][r];
      }
}

// ---------------- attention + Wot transpose + z-share, one launch -------------
// blocks [0,4096): GQA-batched sliding-window attention (1 wave per (b,i,kh))
//                  + 768 zero-chunks per block (hidden under attn latency).
// blocks [4096,8192): Wot 32x32 transpose tiles (needed only by GEMM2).
__global__ void attn_k(const unsigned short* __restrict__ QKV,
                       unsigned short* __restrict__ AO,
                       float* __restrict__ attn_out,
                       const float* __restrict__ cosT,
                       const float* __restrict__ sinT,
                       const float* __restrict__ wo,
                       unsigned short* __restrict__ Wot) {
  __shared__ float tile[32][33];
  const int bid = blockIdx.x, t = threadIdx.x;

  if (bid >= 4096) {   // ---- Wot transpose part ----
    int lb = bid - 4096;
    const int n0 = (lb & 63) * 32, k0 = (lb >> 6) * 32;
    const int tx = t & 31, ty = t >> 5;
    #pragma unroll
    for (int r = 0; r < 32; r += 8)
      tile[ty + r][tx] = wo[(size_t)(k0 + ty + r) * HID + n0 + tx];
    __syncthreads();
    #pragma unroll
    for (int r = 0; r < 32; r += 8)
      Wot[(size_t)(n0 + ty + r) * HID + k0 + tx] = f2bf(tile[tx][ty + r]);
    return;
  }

  // ---- z-fill side job: 3 chunks/thread, issued first (retire under attn) ---
  #pragma unroll
  for (int s = 0; s < 3; ++s) {
    long g = (long)bid * ZA_CHUNK + s * 256 + t;   // g < ZA_TOTAL
    int c = (int)(g & 511);
    int qi = (int)((g >> 9) & (SEQ - 1));
    int zhi = qi >> 2;
    int zlo = (qi >= 2 ? qi - 2 : 0) >> 2;
    if (c != zhi && c != zlo) {
      f32x4 z = {0.f, 0.f, 0.f, 0.f};
      __builtin_nontemporal_store(z, (f32x4*)attn_out + g);
    }
  }

  // ---- attention ----
  int unit = bid * 4 + (t >> 6);  // (b*S + i)*NKVH + kh
  int lane = t & 63;
  int kh = unit & (NKVH - 1);
  int mi = unit >> 2;            // b*S + i
  int i = mi & (SEQ - 1);
  int b = mi >> 11;
  const float SCALE = 0.08838834764831845f;  // 1/sqrt(128)

  float ci = cosT[i * 64 + lane], si = sinT[i * 64 + lane];

  // q: 4 heads, roped in-lane
  float qa[4], qb[4];
  #pragma unroll
  for (int hh = 0; hh < 4; ++hh) {
    ushort2 qv = *(const ushort2*)(QKV + (size_t)mi * QKV_N + (kh * 4 + hh) * HDIM + 2 * lane);
    float a = bf2f(qv.x), bb = bf2f(qv.y);
    qa[hh] = a * ci - bb * si;
    qb[hh] = a * si + bb * ci;
  }

  // k (roped) and v for the 3 window positions
  float ka[3], kb[3], va[3], vb[3];
  #pragma unroll
  for (int jj = 0; jj < 3; ++jj) { ka[jj] = kb[jj] = va[jj] = vb[jj] = 0.f; }
  #pragma unroll
  for (int jj = 0; jj < 3; ++jj) {
    int j = i - 2 + jj;
    if (j >= 0) {   // wave-uniform
      const unsigned short* rp = QKV + (size_t)(mi - i + j) * QKV_N;
      float cj = cosT[j * 64 + lane], sj = sinT[j * 64 + lane];
      ushort2 kv = *(const ushort2*)(rp + 2048 + kh * HDIM + 2 * lane);
      float a = bf2f(kv.x), bb = bf2f(kv.y);
      ka[jj] = a * cj - bb * sj;
      kb[jj] = a * sj + bb * cj;
      ushort2 vv = *(const ushort2*)(rp + 2560 + kh * HDIM + 2 * lane);
      va[jj] = bf2f(vv.x); vb[jj] = bf2f(vv.y);
    }
  }

  // 12 dot products (butterfly reduce; all lanes end with the sum)
  float d[4][3];
  #pragma unroll
  for (int hh = 0; hh < 4; ++hh)
    #pragma unroll
    for (int jj = 0; jj < 3; ++jj) {
      int j = i - 2 + jj;
      float part = qa[hh] * ka[jj] + qb[hh] * kb[jj];
      #pragma unroll
      for (int o = 32; o; o >>= 1) part += __shfl_xor(part, o, 64);
      d[hh][jj] = (j >= 0) ? part * SCALE : -1e30f;
    }

  int rowb = (b * NH + kh * 4) * SEQ + i;   // attn row of head hh=0
  int lo = (i >= 2 ? i - 2 : 0) >> 2;
  int hi = i >> 2;
  #pragma unroll
  for (int hh = 0; hh < 4; ++hh) {
    float mx = fmaxf(fmaxf(d[hh][0], d[hh][1]), d[hh][2]);
    float p0 = __expf(d[hh][0] - mx), p1 = __expf(d[hh][1] - mx), p2 = __expf(d[hh][2] - mx);
    float inv = 1.0f / (p0 + p1 + p2);
    float aw0 = p0 * inv, aw1 = p1 * inv, aw2 = p2 * inv;

    float oa = aw0 * va[0] + aw1 * va[1] + aw2 * va[2];
    float ob = aw0 * vb[0] + aw1 * vb[1] + aw2 * vb[2];
    ushort2 ov; ov.x = f2bf(oa); ov.y = f2bf(ob);
    *(ushort2*)(AO + (size_t)mi * HID + (kh * 4 + hh) * HDIM + 2 * lane) = ov;

    // diagonal f32x4 chunk(s): lanes 2*hh and 2*hh+1 (all lanes hold aw*)
    if (lane == 2 * hh || (lane == 2 * hh + 1 && hi != lo)) {
      int c = (lane == 2 * hh) ? lo : hi;
      f32x4 val = {0.f, 0.f, 0.f, 0.f};
      float aw[3] = {aw0, aw1, aw2};
      #pragma unroll
      for (int q = 0; q < 4; ++q) {
        int j = c * 4 + q;
        int dd = j - (i - 2);
        if (dd >= 0 && dd < 3 && j <= i) val[q] = aw[dd];
      }
      __builtin_nontemporal_store(
          val, (f32x4*)(attn_out + ((size_t)rowb + (size_t)hh * SEQ) * SEQ) + c);
    }
  }
}

extern "C" void kernel_launch(void* const* d_in, const int* in_sizes, int n_in,
                              void* d_out, int out_size, void* d_ws, size_t ws_size,
                              hipStream_t stream) {
  const float* x    = (const float*)d_in[0];
  const float* wq   = (const float*)d_in[1];
  const float* wk   = (const float*)d_in[2];
  const float* wv   = (const float*)d_in[3];
  const float* wo   = (const float*)d_in[4];
  const float* cosT = (const float*)d_in[5];
  const float* sinT = (const float*)d_in[6];

  float* out  = (float*)d_out;            // [4096][2048] f32
  float* attn = out + OUT0_ELEMS;         // [2][16][2048][2048] f32

  // workspace layout (~76 MB)
  char* ws = (char*)d_ws;
  unsigned short* Xbf   = (unsigned short*)ws;  ws += (size_t)MTOT * HID * 2;
  unsigned short* Wqkvt = (unsigned short*)ws;  ws += (size_t)QKV_N * HID * 2;
  unsigned short* Wot   = (unsigned short*)ws;  ws += (size_t)HID * HID * 2;
  unsigned short* QKV   = (unsigned short*)ws;  ws += (size_t)MTOT * QKV_N * 2;
  unsigned short* AO    = (unsigned short*)ws;

  // prep: x cvt + wq/wk/wv transposes (Wot lives in attn_k)
  prep_k<<<14336, 256, 0, stream>>>(x, wq, wk, wv, Xbf, Wqkvt);

  // fused QKV projection -> bf16 (un-roped); zeroes attn chunks [ZA, ZA+Z1)
  gemm_bt_k<true><<<dim3(QKV_N / 128, MTOT / 128), 256, 0, stream>>>(
      Xbf, Wqkvt, QKV, MTOT, QKV_N, HID, (f32x4*)attn, ZA_TOTAL, Z1_CHUNK);

  // attention (+z-share [0,ZA) + diagonal probs) and Wot transpose, one launch
  attn_k<<<8192, 256, 0, stream>>>(QKV, AO, attn, cosT, sinT, wo, Wot);

  // output projection -> d_out f32; zeroes attn chunks [ZA+Z1, end)
  gemm_bt_k<false><<<dim3(HID / 128, MTOT / 128), 256, 0, stream>>>(
      AO, Wot, out, MTOT, HID, HID, (f32x4*)attn, ZA_TOTAL + Z1_TOTAL, Z2_CHUNK);
}

// Round 19
// 183.361 us; speedup vs baseline: 1.0517x; 1.0517x over previous
//
#include <hip/hip_runtime.h>

// Problem constants
#define SEQ 2048
#define HID 2048
#define NH 16
#define NKVH 4
#define HDIM 128
#define NB 2
#define MTOT (NB * SEQ)          // 4096 rows
#define QKV_N (NH * HDIM + 2 * NKVH * HDIM)  // 3072
#define OUT0_ELEMS (NB * SEQ * HID)          // 8,388,608
#define ATTN_ELEMS ((size_t)NB * NH * SEQ * SEQ) // 134,217,728
// zero-fill partition (R15 config — measured best, 188.1 us; R18's G2->G1
// shift regressed):  attn 4096 x 768 + GEMM1 768 x 21952 + GEMM2 512 x 26464
#define ZA_CHUNK 768
#define ZA_TOTAL ((long)4096 * ZA_CHUNK)     // 3,145,728
#define Z1_CHUNK 21952
#define Z1_TOTAL ((long)768 * Z1_CHUNK)      // 16,859,136
#define Z2_CHUNK 26464                       // 512*26464 = 13,549,568; sum = 33,554,432

typedef __bf16 bf16x8 __attribute__((ext_vector_type(8)));
typedef float f32x4 __attribute__((ext_vector_type(4)));

__device__ __forceinline__ unsigned short f2bf(float f) {
  unsigned int u = __float_as_uint(f);
  u += 0x7FFFu + ((u >> 16) & 1u);   // round-to-nearest-even
  return (unsigned short)(u >> 16);
}
__device__ __forceinline__ float bf2f(unsigned short u) {
  return __uint_as_float(((unsigned int)u) << 16);
}

// ---------------- fused prep: x->bf16 cvt + wq/wk/wv transpose+cvt ------------
// (Wot transpose lives in attn_k's grid — only GEMM2 needs it.)
__global__ __launch_bounds__(256) void prep_k(
    const float* __restrict__ x, const float* __restrict__ wq,
    const float* __restrict__ wk, const float* __restrict__ wv,
    unsigned short* __restrict__ Xbf, unsigned short* __restrict__ Wqkvt) {
  __shared__ float tile[32][33];
  const int bid = blockIdx.x, t = threadIdx.x;
  if (bid < 8192) {
    int i = bid * 256 + t;
    float4 v = ((const float4*)x)[i];
    ushort4 o;
    o.x = f2bf(v.x); o.y = f2bf(v.y); o.z = f2bf(v.z); o.w = f2bf(v.w);
    ((ushort4*)Xbf)[i] = o;
    return;
  }
  int lb = bid - 8192;
  const float* W; unsigned short* Wt; int gx, N;
  if (lb < 4096)      { W = wq; Wt = Wqkvt;                       gx = 64; N = 2048; }
  else if (lb < 5120) { W = wk; Wt = Wqkvt + (size_t)2048 * HID;  gx = 16; N = 512;  lb -= 4096; }
  else                { W = wv; Wt = Wqkvt + (size_t)2560 * HID;  gx = 16; N = 512;  lb -= 5120; }
  const int n0 = (lb % gx) * 32, k0 = (lb / gx) * 32;
  const int tx = t & 31, ty = t >> 5;
  #pragma unroll
  for (int r = 0; r < 32; r += 8)
    tile[ty + r][tx] = W[(size_t)(k0 + ty + r) * N + n0 + tx];
  __syncthreads();
  #pragma unroll
  for (int r = 0; r < 32; r += 8)
    Wt[(size_t)(n0 + ty + r) * HID + k0 + tx] = f2bf(tile[tx][ty + r]);
}

// ---------------- bf16 MFMA GEMM (m97 structure, BK=64) + fused attn-zero job -
// 128x128 tile, 4 waves x 4x4 frags of 16x16x32, BK=64, global_load_lds w=16,
// XCD-aware swizzle, zero-stores in compute phase.
template <bool OUT_BF16>
__global__ __launch_bounds__(256, 4) void gemm_bt_k(
    const unsigned short* __restrict__ A, const unsigned short* __restrict__ Bt,
    void* __restrict__ Cv, int M, int N, int K,
    f32x4* __restrict__ attn4, long zoff, int zchunk) {
  __shared__ unsigned short As[128 * 64];   // 16 KB
  __shared__ unsigned short Bs[128 * 64];   // 16 KB
  const int t = threadIdx.x;
  // XCD swizzle (nwg % 8 == 0 for both GEMMs)
  const int nbx = gridDim.x;
  const int rawbid = blockIdx.y * nbx + blockIdx.x;
  const int nwg = nbx * gridDim.y;
  const int sw = (rawbid & 7) * (nwg >> 3) + (rawbid >> 3);
  const int row0 = (sw / nbx) << 7;
  const int col0 = (sw % nbx) << 7;
  const int lane = t & 63;
  const int wave = t >> 6;
  const int wr = (wave >> 1) << 6;
  const int wc = (wave & 1) << 6;
  const int lrow = lane & 15;
  const int kofs = (lane >> 4) << 3;

  const long zbase = zoff + (long)rawbid * zchunk;

  f32x4 acc[4][4];
  #pragma unroll
  for (int a = 0; a < 4; ++a)
    #pragma unroll
    for (int b = 0; b < 4; ++b)
      #pragma unroll
      for (int r = 0; r < 4; ++r) acc[a][b][r] = 0.f;

  // staging: tile = 128 rows x 64 cols bf16 = 1024 x 16B chunks; 256 thr x 4.
  const unsigned short* Ab = A + (size_t)row0 * K;
  const unsigned short* Bb = Bt + (size_t)col0 * K;

  const int nk = K >> 6;
  for (int kt = 0; kt < nk; ++kt) {
    const int k0 = kt << 6;
    if (kt) __syncthreads();
    #pragma unroll
    for (int i = 0; i < 4; ++i) {
      const int c = i * 256 + t;          // all 1024 chunks covered
      const int row = c >> 3, c8 = (c & 7) << 3;
      __builtin_amdgcn_global_load_lds(
          (const __attribute__((address_space(1))) void*)(Ab + (size_t)row * K + k0 + c8),
          (__attribute__((address_space(3))) void*)(As + c * 8), 16, 0, 0);
      __builtin_amdgcn_global_load_lds(
          (const __attribute__((address_space(1))) void*)(Bb + (size_t)row * K + k0 + c8),
          (__attribute__((address_space(3))) void*)(Bs + c * 8), 16, 0, 0);
    }
    __syncthreads();   // compiler drains vmcnt(0)

    // fused attn-zero side job: 4 chunks per K-step (retire during MFMA phase)
    #pragma unroll
    for (int s = 0; s < 4; ++s) {
      int il = (kt * 4 + s) * 256 + t;
      if (il < zchunk) {
        long g = zbase + il;
        int c = (int)(g & 511);               // f32x4 chunk within attn row
        int i = (int)((g >> 9) & (SEQ - 1));  // query index of this row
        int hi = i >> 2;
        int lo = (i >= 2 ? i - 2 : 0) >> 2;
        if (c != hi && c != lo) {
          f32x4 z = {0.f, 0.f, 0.f, 0.f};
          __builtin_nontemporal_store(z, attn4 + g);
        }
      }
    }

    #pragma unroll
    for (int ks = 0; ks < 2; ++ks) {
      bf16x8 af[4], bfr[4];
      #pragma unroll
      for (int mf = 0; mf < 4; ++mf)
        af[mf] = *(const bf16x8*)(As + ((wr + mf * 16 + lrow) << 6) + (ks << 5) + kofs);
      #pragma unroll
      for (int nf = 0; nf < 4; ++nf)
        bfr[nf] = *(const bf16x8*)(Bs + ((wc + nf * 16 + lrow) << 6) + (ks << 5) + kofs);
      #pragma unroll
      for (int mf = 0; mf < 4; ++mf)
        #pragma unroll
        for (int nf = 0; nf < 4; ++nf)
          acc[mf][nf] = __builtin_amdgcn_mfma_f32_16x16x32_bf16(af[mf], bfr[nf],
                                                                acc[mf][nf], 0, 0, 0);
    }
  }

  // epilogue: D mapping col=lane&15, row=(lane>>4)*4+reg  [measured m89/m91]
  const int cr = row0 + wr + ((lane >> 4) << 2);
  const int cc = col0 + wc + (lane & 15);
  #pragma unroll
  for (int mf = 0; mf < 4; ++mf)
    #pragma unroll
    for (int nf = 0; nf < 4; ++nf)
      #pragma unroll
      for (int r = 0; r < 4; ++r) {
        size_t idx = (size_t)(cr + mf * 16 + r) * N + cc + nf * 16;
        if constexpr (OUT_BF16)
          ((unsigned short*)Cv)[idx] = f2bf(acc[mf][nf][r]);
        else
          ((float*)Cv)[idx] = acc[mf][nf][r];
      }
}

// ---------------- attention + Wot transpose + z-share, one launch -------------
// blocks [0,4096): GQA-batched sliding-window attention (1 wave per (b,i,kh))
//                  + 768 zero-chunks per block (hidden under attn latency).
// blocks [4096,8192): Wot 32x32 transpose tiles (needed only by GEMM2).
__global__ void attn_k(const unsigned short* __restrict__ QKV,
                       unsigned short* __restrict__ AO,
                       float* __restrict__ attn_out,
                       const float* __restrict__ cosT,
                       const float* __restrict__ sinT,
                       const float* __restrict__ wo,
                       unsigned short* __restrict__ Wot) {
  __shared__ float tile[32][33];
  const int bid = blockIdx.x, t = threadIdx.x;

  if (bid >= 4096) {   // ---- Wot transpose part ----
    int lb = bid - 4096;
    const int n0 = (lb & 63) * 32, k0 = (lb >> 6) * 32;
    const int tx = t & 31, ty = t >> 5;
    #pragma unroll
    for (int r = 0; r < 32; r += 8)
      tile[ty + r][tx] = wo[(size_t)(k0 + ty + r) * HID + n0 + tx];
    __syncthreads();
    #pragma unroll
    for (int r = 0; r < 32; r += 8)
      Wot[(size_t)(n0 + ty + r) * HID + k0 + tx] = f2bf(tile[tx][ty + r]);
    return;
  }

  // ---- z-fill side job: 3 chunks/thread, issued first (retire under attn) ---
  #pragma unroll
  for (int s = 0; s < 3; ++s) {
    long g = (long)bid * ZA_CHUNK + s * 256 + t;   // g < ZA_TOTAL
    int c = (int)(g & 511);
    int qi = (int)((g >> 9) & (SEQ - 1));
    int zhi = qi >> 2;
    int zlo = (qi >= 2 ? qi - 2 : 0) >> 2;
    if (c != zhi && c != zlo) {
      f32x4 z = {0.f, 0.f, 0.f, 0.f};
      __builtin_nontemporal_store(z, (f32x4*)attn_out + g);
    }
  }

  // ---- attention ----
  int unit = bid * 4 + (t >> 6);  // (b*S + i)*NKVH + kh
  int lane = t & 63;
  int kh = unit & (NKVH - 1);
  int mi = unit >> 2;            // b*S + i
  int i = mi & (SEQ - 1);
  int b = mi >> 11;
  const float SCALE = 0.08838834764831845f;  // 1/sqrt(128)

  float ci = cosT[i * 64 + lane], si = sinT[i * 64 + lane];

  // q: 4 heads, roped in-lane
  float qa[4], qb[4];
  #pragma unroll
  for (int hh = 0; hh < 4; ++hh) {
    ushort2 qv = *(const ushort2*)(QKV + (size_t)mi * QKV_N + (kh * 4 + hh) * HDIM + 2 * lane);
    float a = bf2f(qv.x), bb = bf2f(qv.y);
    qa[hh] = a * ci - bb * si;
    qb[hh] = a * si + bb * ci;
  }

  // k (roped) and v for the 3 window positions
  float ka[3], kb[3], va[3], vb[3];
  #pragma unroll
  for (int jj = 0; jj < 3; ++jj) { ka[jj] = kb[jj] = va[jj] = vb[jj] = 0.f; }
  #pragma unroll
  for (int jj = 0; jj < 3; ++jj) {
    int j = i - 2 + jj;
    if (j >= 0) {   // wave-uniform
      const unsigned short* rp = QKV + (size_t)(mi - i + j) * QKV_N;
      float cj = cosT[j * 64 + lane], sj = sinT[j * 64 + lane];
      ushort2 kv = *(const ushort2*)(rp + 2048 + kh * HDIM + 2 * lane);
      float a = bf2f(kv.x), bb = bf2f(kv.y);
      ka[jj] = a * cj - bb * sj;
      kb[jj] = a * sj + bb * cj;
      ushort2 vv = *(const ushort2*)(rp + 2560 + kh * HDIM + 2 * lane);
      va[jj] = bf2f(vv.x); vb[jj] = bf2f(vv.y);
    }
  }

  // 12 dot products (butterfly reduce; all lanes end with the sum)
  float d[4][3];
  #pragma unroll
  for (int hh = 0; hh < 4; ++hh)
    #pragma unroll
    for (int jj = 0; jj < 3; ++jj) {
      int j = i - 2 + jj;
      float part = qa[hh] * ka[jj] + qb[hh] * kb[jj];
      #pragma unroll
      for (int o = 32; o; o >>= 1) part += __shfl_xor(part, o, 64);
      d[hh][jj] = (j >= 0) ? part * SCALE : -1e30f;
    }

  int rowb = (b * NH + kh * 4) * SEQ + i;   // attn row of head hh=0
  int lo = (i >= 2 ? i - 2 : 0) >> 2;
  int hi = i >> 2;
  #pragma unroll
  for (int hh = 0; hh < 4; ++hh) {
    float mx = fmaxf(fmaxf(d[hh][0], d[hh][1]), d[hh][2]);
    float p0 = __expf(d[hh][0] - mx), p1 = __expf(d[hh][1] - mx), p2 = __expf(d[hh][2] - mx);
    float inv = 1.0f / (p0 + p1 + p2);
    float aw0 = p0 * inv, aw1 = p1 * inv, aw2 = p2 * inv;

    float oa = aw0 * va[0] + aw1 * va[1] + aw2 * va[2];
    float ob = aw0 * vb[0] + aw1 * vb[1] + aw2 * vb[2];
    ushort2 ov; ov.x = f2bf(oa); ov.y = f2bf(ob);
    *(ushort2*)(AO + (size_t)mi * HID + (kh * 4 + hh) * HDIM + 2 * lane) = ov;

    // diagonal f32x4 chunk(s): lanes 2*hh and 2*hh+1 (all lanes hold aw*)
    if (lane == 2 * hh || (lane == 2 * hh + 1 && hi != lo)) {
      int c = (lane == 2 * hh) ? lo : hi;
      f32x4 val = {0.f, 0.f, 0.f, 0.f};
      float aw[3] = {aw0, aw1, aw2};
      #pragma unroll
      for (int q = 0; q < 4; ++q) {
        int j = c * 4 + q;
        int dd = j - (i - 2);
        if (dd >= 0 && dd < 3 && j <= i) val[q] = aw[dd];
      }
      __builtin_nontemporal_store(
          val, (f32x4*)(attn_out + ((size_t)rowb + (size_t)hh * SEQ) * SEQ) + c);
    }
  }
}

extern "C" void kernel_launch(void* const* d_in, const int* in_sizes, int n_in,
                              void* d_out, int out_size, void* d_ws, size_t ws_size,
                              hipStream_t stream) {
  const float* x    = (const float*)d_in[0];
  const float* wq   = (const float*)d_in[1];
  const float* wk   = (const float*)d_in[2];
  const float* wv   = (const float*)d_in[3];
  const float* wo   = (const float*)d_in[4];
  const float* cosT = (const float*)d_in[5];
  const float* sinT = (const float*)d_in[6];

  float* out  = (float*)d_out;            // [4096][2048] f32
  float* attn = out + OUT0_ELEMS;         // [2][16][2048][2048] f32

  // workspace layout (~76 MB)
  char* ws = (char*)d_ws;
  unsigned short* Xbf   = (unsigned short*)ws;  ws += (size_t)MTOT * HID * 2;
  unsigned short* Wqkvt = (unsigned short*)ws;  ws += (size_t)QKV_N * HID * 2;
  unsigned short* Wot   = (unsigned short*)ws;  ws += (size_t)HID * HID * 2;
  unsigned short* QKV   = (unsigned short*)ws;  ws += (size_t)MTOT * QKV_N * 2;
  unsigned short* AO    = (unsigned short*)ws;

  // prep: x cvt + wq/wk/wv transposes (Wot lives in attn_k)
  prep_k<<<14336, 256, 0, stream>>>(x, wq, wk, wv, Xbf, Wqkvt);

  // fused QKV projection -> bf16 (un-roped); zeroes attn chunks [ZA, ZA+Z1)
  gemm_bt_k<true><<<dim3(QKV_N / 128, MTOT / 128), 256, 0, stream>>>(
      Xbf, Wqkvt, QKV, MTOT, QKV_N, HID, (f32x4*)attn, ZA_TOTAL, Z1_CHUNK);

  // attention (+z-share [0,ZA) + diagonal probs) and Wot transpose, one launch
  attn_k<<<8192, 256, 0, stream>>>(QKV, AO, attn, cosT, sinT, wo, Wot);

  // output projection -> d_out f32; zeroes attn chunks [ZA+Z1, end)
  gemm_bt_k<false><<<dim3(HID / 128, MTOT / 128), 256, 0, stream>>>(
      AO, Wot, out, MTOT, HID, HID, (f32x4*)attn, ZA_TOTAL + Z1_TOTAL, Z2_CHUNK);
}